// Round 9
// baseline (323.437 us; speedup 1.0000x reference)
//
#include <hip/hip_runtime.h>
#include <hip/hip_bf16.h>

// FlexibleGCN forward on MI355X — Round 9: MFMA bf16 GEMMs.
//  * gemm1/gemm2/fc use v_mfma_f32_16x16x32_bf16: 4 waves/block, 64 rows/block,
//    a-frags direct from global (A[m=lane&15][k=quad*8+j]), W transposed->bf16
//    in LDS (b-frag = 8 contiguous k at row n, n=lane&15), C/D col=lane&15,
//    row=quad*4+reg (learn_hip m89).
//  * aggs at the random-gather ceiling (~3.5 TB/s) — unchanged from R8.
//  * CSR build unchanged.

constexpr int IN_DIM  = 128;
constexpr int HDIM    = 64;
constexpr int NBLK_A  = 256;
constexpr int BSH     = 8;
constexpr int MAXNB   = 512;

typedef __attribute__((ext_vector_type(8))) short short8;
typedef __attribute__((ext_vector_type(4))) float floatx4;

__device__ __forceinline__ float bf2f(unsigned int u) {
    return __uint_as_float(u << 16);
}
__device__ __forceinline__ unsigned short f2bf_bits(float f) {
    __hip_bfloat16 b = __float2bfloat16(f);
    return *(unsigned short*)&b;
}

// ---------- CSR build ----------

__global__ void binA_count(const int* __restrict__ dst, int* __restrict__ histg,
                           int E, int NB, int chunk) {
    __shared__ int h[MAXNB];
    for (int i = threadIdx.x; i < NB; i += 256) h[i] = 0;
    __syncthreads();
    int beg = blockIdx.x * chunk;
    int end = min(E, beg + chunk);
    for (int e = beg + threadIdx.x; e < end; e += 256)
        atomicAdd(&h[dst[e] >> BSH], 1);
    __syncthreads();
    for (int i = threadIdx.x; i < NB; i += 256)
        histg[i * NBLK_A + blockIdx.x] = h[i];
}

__global__ void binA_scanblocks(int* __restrict__ histg, int* __restrict__ btot) {
    __shared__ int sm[NBLK_A];
    int tid = threadIdx.x;
    int v = histg[blockIdx.x * NBLK_A + tid];
    sm[tid] = v;
    __syncthreads();
    for (int off = 1; off < NBLK_A; off <<= 1) {
        int t = (tid >= off) ? sm[tid - off] : 0;
        __syncthreads();
        sm[tid] += t;
        __syncthreads();
    }
    histg[blockIdx.x * NBLK_A + tid] = sm[tid] - v;   // exclusive
    if (tid == NBLK_A - 1) btot[blockIdx.x] = sm[tid];
}

__global__ void binA_scanbuckets(const int* __restrict__ btot, int* __restrict__ bucketbase,
                                 int NB) {
    __shared__ int sm[MAXNB];
    int tid = threadIdx.x;    // blockDim = MAXNB
    int v = (tid < NB) ? btot[tid] : 0;
    sm[tid] = v;
    __syncthreads();
    for (int off = 1; off < MAXNB; off <<= 1) {
        int t = (tid >= off) ? sm[tid - off] : 0;
        __syncthreads();
        sm[tid] += t;
        __syncthreads();
    }
    if (tid < NB) bucketbase[tid] = sm[tid] - v;
    if (tid == MAXNB - 1) bucketbase[NB] = sm[tid];   // == E
}

__global__ void binA_scatter(const int* __restrict__ src, const int* __restrict__ dst,
                             const int* __restrict__ histg, const int* __restrict__ bucketbase,
                             int* __restrict__ staging, int E, int NB, int chunk) {
    __shared__ int cur[MAXNB];
    for (int i = threadIdx.x; i < NB; i += 256)
        cur[i] = bucketbase[i] + histg[i * NBLK_A + blockIdx.x];
    __syncthreads();
    int beg = blockIdx.x * chunk;
    int end = min(E, beg + chunk);
    for (int e = beg + threadIdx.x; e < end; e += 256) {
        int s = src[e];
        int d = dst[e];
        int pos = atomicAdd(&cur[d >> BSH], 1);
        staging[pos] = (s << BSH) | (d & 255);
    }
}

__global__ void binB_finalize(const int* __restrict__ staging, const int* __restrict__ bucketbase,
                              int* __restrict__ rowptr, int* __restrict__ esrc,
                              float* __restrict__ dinv, int N, int NB) {
    __shared__ int cnt[256], sm[256], cur[256];
    int tid = threadIdx.x;
    int b = blockIdx.x;
    int node0 = b << BSH;
    int nloc = min(256, N - node0);
    int ebeg = bucketbase[b], eend = bucketbase[b + 1];
    cnt[tid] = 0;
    __syncthreads();
    for (int e = ebeg + tid; e < eend; e += 256)
        atomicAdd(&cnt[staging[e] & 255], 1);
    __syncthreads();
    int v = cnt[tid];
    sm[tid] = v;
    __syncthreads();
    for (int off = 1; off < 256; off <<= 1) {
        int t = (tid >= off) ? sm[tid - off] : 0;
        __syncthreads();
        sm[tid] += t;
        __syncthreads();
    }
    int excl = sm[tid] - v;
    cur[tid] = excl;
    __syncthreads();
    if (tid < nloc) {
        rowptr[node0 + tid] = ebeg + excl;
        dinv[node0 + tid] = rsqrtf((float)v + 1.0f);   // +1 self-loop
    }
    if (b == 0 && tid == 0) rowptr[N] = bucketbase[NB];
    for (int e = ebeg + tid; e < eend; e += 256) {
        int p = staging[e];
        int pos = ebeg + atomicAdd(&cur[p & 255], 1);
        esrc[pos] = p >> BSH;
    }
}

// ---------- MFMA dense layers ----------

// Y[n][64] = X[n][K] @ W[K][64]; optional *dinv[row] (SCALE) xor +bias (BIAS).
// 256 threads = 4 waves; wave = 16 rows; block = 64 rows.
// a-frag: A[m=lane&15][k=quad*8+j] straight from global (bf16 or fp32->cvt).
// b-frag: Wt[n=lane&15 + 16*nt][k=quad*8+j] from LDS (W transposed, bf16).
// C/D: col=lane&15, row=quad*4+reg.
template<int K, bool IBF16, bool SCALE, bool BIAS, bool OBF16>
__device__ __forceinline__ void mfma_gemm_body(
        const void* __restrict__ Xv, const float* __restrict__ W,
        const float* __restrict__ bias, const float* __restrict__ dinv,
        void* __restrict__ Yv, int n) {
    constexpr int KP = K + 8;                 // +8 halves: 2-way bank alias (free)
    __shared__ unsigned short Wt[64 * KP];
    const int tid = threadIdx.x;
    // stage W^T as bf16: element W[k][c] -> Wt[c*KP + k]
    for (int i = tid; i < K * 64; i += 256) {
        int k = i % K, c = i / K;
        Wt[c * KP + k] = f2bf_bits(W[k * 64 + c]);
    }
    __syncthreads();

    const int wid  = tid >> 6;
    const int lane = tid & 63;
    const int q    = lane >> 4;               // quad 0..3
    const int m    = lane & 15;
    const int rbase = blockIdx.x * 64 + wid * 16;
    int lrow = rbase + m;
    if (lrow > n - 1) lrow = n - 1;           // clamp (stores guarded)

    // a-frags for all K-chunks (independent loads -> deep MLP)
    short8 a[K / 32];
#pragma unroll
    for (int c = 0; c < K / 32; ++c) {
        if (IBF16) {
            a[c] = *(const short8*)((const unsigned short*)Xv + (size_t)lrow * K + c * 32 + q * 8);
        } else {
            const float* xp = (const float*)Xv + (size_t)lrow * K + c * 32 + q * 8;
            floatx4 f0 = *(const floatx4*)xp;
            floatx4 f1 = *(const floatx4*)(xp + 4);
            short8 t;
            t[0] = (short)f2bf_bits(f0[0]); t[1] = (short)f2bf_bits(f0[1]);
            t[2] = (short)f2bf_bits(f0[2]); t[3] = (short)f2bf_bits(f0[3]);
            t[4] = (short)f2bf_bits(f1[0]); t[5] = (short)f2bf_bits(f1[1]);
            t[6] = (short)f2bf_bits(f1[2]); t[7] = (short)f2bf_bits(f1[3]);
            a[c] = t;
        }
    }

    floatx4 acc[4];
#pragma unroll
    for (int nt = 0; nt < 4; ++nt) acc[nt] = (floatx4){0.f, 0.f, 0.f, 0.f};

#pragma unroll
    for (int c = 0; c < K / 32; ++c) {
#pragma unroll
        for (int nt = 0; nt < 4; ++nt) {
            short8 b = *(const short8*)&Wt[(nt * 16 + m) * KP + c * 32 + q * 8];
            acc[nt] = __builtin_amdgcn_mfma_f32_16x16x32_bf16(a[c], b, acc[nt], 0, 0, 0);
        }
    }

#pragma unroll
    for (int r = 0; r < 4; ++r) {
        int node = rbase + q * 4 + r;
        if (node < n) {
            float d = SCALE ? dinv[node] : 1.0f;
#pragma unroll
            for (int nt = 0; nt < 4; ++nt) {
                float v = acc[nt][r];
                if (BIAS) v += bias[nt * 16 + m];
                v *= d;
                if (OBF16)
                    ((unsigned short*)Yv)[(size_t)node * 64 + nt * 16 + m] = f2bf_bits(v);
                else
                    ((float*)Yv)[(size_t)node * 64 + nt * 16 + m] = v;
            }
        }
    }
}

__global__ __launch_bounds__(256) void gemm1_kernel(
        const float* X, const float* W, const float* dinv, void* Y, int n) {
    mfma_gemm_body<IN_DIM, false, true, false, true>(X, W, nullptr, dinv, Y, n);
}
__global__ __launch_bounds__(256) void gemm2_kernel(
        const void* X, const float* W, const float* dinv, void* Y, int n) {
    mfma_gemm_body<HDIM, true, true, false, true>(X, W, nullptr, dinv, Y, n);
}
__global__ __launch_bounds__(256) void fc_kernel(
        const float* X, const float* W, const float* bias, void* Y, int n) {
    mfma_gemm_body<HDIM, false, false, true, false>(X, W, bias, nullptr, Y, n);
}

// ---------- agg (unchanged from R8) ----------

template<bool OBF16>
__device__ __forceinline__ void agg_body(
        const unsigned short* __restrict__ hp, const int* __restrict__ esrc,
        const int* __restrict__ rowptr, const float* __restrict__ dinv,
        const float* __restrict__ bias, void* __restrict__ out, int n) {
    int node = blockIdx.x * 4 + (threadIdx.x >> 6);
    if (node >= n) return;
    int lane = threadIdx.x & 63;
    int half = lane >> 5;
    int l = lane & 31;
    const unsigned int* hp32 = (const unsigned int*)hp;   // row s -> hp32[s*32 + l]
    int beg = rowptr[node], end = rowptr[node + 1];

    float ax = 0.f, ay = 0.f;
    {   // self-loop, counted by half 0 only
        unsigned int u = hp32[(size_t)node * 32 + l];
        if (half == 0) { ax = bf2f(u & 0xffff); ay = bf2f(u >> 16); }
    }
    int k = beg;
    for (; k + 16 <= end; k += 16) {
        int s[8];
#pragma unroll
        for (int i = 0; i < 8; ++i) s[i] = esrc[k + 2 * i + half];
        unsigned int u[8];
#pragma unroll
        for (int i = 0; i < 8; ++i) u[i] = hp32[(size_t)s[i] * 32 + l];
        float vx[8], vy[8];
#pragma unroll
        for (int i = 0; i < 8; ++i) { vx[i] = bf2f(u[i] & 0xffff); vy[i] = bf2f(u[i] >> 16); }
        ax += ((vx[0] + vx[1]) + (vx[2] + vx[3])) + ((vx[4] + vx[5]) + (vx[6] + vx[7]));
        ay += ((vy[0] + vy[1]) + (vy[2] + vy[3])) + ((vy[4] + vy[5]) + (vy[6] + vy[7]));
    }
    if (k < end) {
        int s[8];
#pragma unroll
        for (int i = 0; i < 8; ++i) s[i] = esrc[min(k + 2 * i + half, end - 1)];
        unsigned int u[8];
#pragma unroll
        for (int i = 0; i < 8; ++i) u[i] = hp32[(size_t)s[i] * 32 + l];
        float tx = 0.f, ty = 0.f;
#pragma unroll
        for (int i = 0; i < 8; ++i) {
            bool mm = (k + 2 * i + half) < end;
            tx += mm ? bf2f(u[i] & 0xffff) : 0.f;
            ty += mm ? bf2f(u[i] >> 16)    : 0.f;
        }
        ax += tx; ay += ty;
    }
    ax += __shfl_xor(ax, 32, 64);
    ay += __shfl_xor(ay, 32, 64);

    if (half == 0) {
        float d = dinv[node];
        float ox = fmaxf(d * ax + bias[2 * l], 0.f);
        float oy = fmaxf(d * ay + bias[2 * l + 1], 0.f);
        if (OBF16) {
            unsigned int packed = (unsigned int)f2bf_bits(ox) | ((unsigned int)f2bf_bits(oy) << 16);
            ((unsigned int*)out)[(size_t)node * 32 + l] = packed;
        } else {
            ((float2*)out)[(size_t)node * 32 + l] = make_float2(ox, oy);
        }
    }
}

__global__ __launch_bounds__(256) void agg1_kernel(
        const unsigned short* hp, const int* esrc, const int* rowptr,
        const float* dinv, const float* bias, void* out, int n) {
    agg_body<true>(hp, esrc, rowptr, dinv, bias, out, n);
}
__global__ __launch_bounds__(256) void agg2_kernel(
        const unsigned short* hp, const int* esrc, const int* rowptr,
        const float* dinv, const float* bias, void* out, int n) {
    agg_body<false>(hp, esrc, rowptr, dinv, bias, out, n);
}

extern "C" void kernel_launch(void* const* d_in, const int* in_sizes, int n_in,
                              void* d_out, int out_size, void* d_ws, size_t ws_size,
                              hipStream_t stream) {
    const float* x   = (const float*)d_in[0];
    const float* W1  = (const float*)d_in[1];
    const float* b1  = (const float*)d_in[2];
    const float* W2  = (const float*)d_in[3];
    const float* b2  = (const float*)d_in[4];
    const float* Wfc = (const float*)d_in[5];
    const float* bfc = (const float*)d_in[6];
    const int*  eidx = (const int*)d_in[7];

    const int N = in_sizes[0] / IN_DIM;     // 100000
    const int E = in_sizes[7] / 2;          // 1600000
    const int* src = eidx;
    const int* dst = eidx + E;

    const int NB    = (N + 255) >> BSH;     // 391 buckets
    const int chunk = (E + NBLK_A - 1) / NBLK_A;

    // ws layout (4B units): rowptr[N+2] | dinv[N] | histg[NB*NBLK_A] | btot[512]
    //   | bucketbase[512] | esrc[E] | bufA[N*64 floats] | bufB[N*64 floats]
    // staging int[E] and hp (bf16) alias bufA; h1 (bf16) aliases bufB.
    int*   rowptr     = (int*)d_ws;
    float* dinv       = (float*)(rowptr + (N + 2));
    int*   histg      = (int*)(dinv + N);
    int*   btot       = histg + (size_t)NB * NBLK_A + (((size_t)NB * NBLK_A) & 1);
    int*   bucketbase = btot + 512;
    int*   esrc       = bucketbase + 512;
    float* bufA       = (float*)(esrc + E + (E & 1));
    float* bufB       = bufA + (size_t)N * HDIM;
    int*   staging    = (int*)bufA;
    unsigned short* hp = (unsigned short*)bufA;   // bf16 bits
    unsigned short* h1 = (unsigned short*)bufB;   // bf16 bits

    float* emb    = (float*)d_out;
    float* logits = emb + (size_t)N * HDIM;

    // ---- CSR build (shared by both conv layers) ----
    binA_count<<<NBLK_A, 256, 0, stream>>>(dst, histg, E, NB, chunk);
    binA_scanblocks<<<NB, NBLK_A, 0, stream>>>(histg, btot);
    binA_scanbuckets<<<1, MAXNB, 0, stream>>>(btot, bucketbase, NB);
    binA_scatter<<<NBLK_A, 256, 0, stream>>>(src, dst, histg, bucketbase, staging, E, NB, chunk);
    binB_finalize<<<NB, 256, 0, stream>>>(staging, bucketbase, rowptr, esrc, dinv, N, NB);

    const int gBlocks = (N + 63) / 64;
    const int aBlocks = (N + 3) / 4;

    // ---- layer 1 ----  hp1 (bf16) aliases staging: staging dead after binB.
    gemm1_kernel<<<gBlocks, 256, 0, stream>>>(x, W1, dinv, hp, N);
    agg1_kernel<<<aBlocks, 256, 0, stream>>>(hp, esrc, rowptr, dinv, b1, h1, N);

    // ---- layer 2 ----
    gemm2_kernel<<<gBlocks, 256, 0, stream>>>(h1, W2, dinv, hp, N);
    agg2_kernel<<<aBlocks, 256, 0, stream>>>(hp, esrc, rowptr, dinv, b2, emb, N);

    // ---- FC head ----
    fc_kernel<<<gBlocks, 256, 0, stream>>>(emb, Wfc, bfc, logits, N);
}